// Round 13
// baseline (283.220 us; speedup 1.0000x reference)
//
#include <hip/hip_runtime.h>

#define S_LEN 1024
#define B_SZ 8
#define F_IN_D 256
#define E_DIM 512
#define INNER_D 1024
#define NH_D 4
#define DH_D 256
#define NROW (B_SZ * S_LEN)   // 8192

typedef _Float16 half8 __attribute__((ext_vector_type(8)));
typedef _Float16 half4_t __attribute__((ext_vector_type(4)));
typedef float v4f __attribute__((ext_vector_type(4)));

// ---------------------------------------------------------------------------
// R19: cast only x + W_in up front (all gemm_in needs). W_up / W_down casts
// ride inside ln_mul / scan_vtrans dispatches (off the critical-path head).
// ---------------------------------------------------------------------------
__global__ __launch_bounds__(256) void cast2_kernel(
    const float* __restrict__ s0, const float* __restrict__ s1,
    _Float16* __restrict__ d0, _Float16* __restrict__ d1,
    int n0, int n1)
{
  int i = (blockIdx.x * 256 + threadIdx.x) * 4;
  const float* s; _Float16* d; int off;
  if (i < n0)           { s = s0; d = d0; off = i; }
  else if (i < n0 + n1) { s = s1; d = d1; off = i - n0; }
  else return;
  float4 v = *(const float4*)(s + off);
  half4_t o = {(_Float16)v.x, (_Float16)v.y, (_Float16)v.z, (_Float16)v.w};
  *(half4_t*)(d + off) = o;
}

// ---------------------------------------------------------------------------
// Pure-f16 MFMA NT GEMM: C[M,N] = A[M,K] @ B[N,K]^T (+ bias), C f32.
// Reg-staged 128x128 structure — proven best.
// ---------------------------------------------------------------------------
#define GBM 128
#define GBN 128
#define GBK 64
#define LDKG (GBK + 8)   // 72 halves = 36 dwords stride

__global__ __launch_bounds__(256) void gemm_h16(
    const _Float16* __restrict__ A, const _Float16* __restrict__ B,
    const float* __restrict__ bias, float* __restrict__ C,
    int M, int N, int K)
{
  __shared__ __align__(16) _Float16 As[GBM][LDKG];
  __shared__ __align__(16) _Float16 Bs[GBN][LDKG];
  const int tid = threadIdx.x;
  const int lane = tid & 63, w = tid >> 6;
  const int wr = w >> 1, wc = w & 1;
  const int quad = lane >> 4, l16 = lane & 15;
  const int bm = blockIdx.y * GBM, bn = blockIdx.x * GBN;
  const int srow = tid >> 1;          // 0..127
  const int scol = (tid & 1) * 32;    // halves

  v4f acc[4][4];
#pragma unroll
  for (int i = 0; i < 4; ++i)
#pragma unroll
    for (int j = 0; j < 4; ++j) acc[i][j] = (v4f){0.f, 0.f, 0.f, 0.f};

  const _Float16* Ap = A + (size_t)(bm + srow) * K + scol;
  const _Float16* Bp = B + (size_t)(bn + srow) * K + scol;
  half8 ap[4], bp[4];
#pragma unroll
  for (int j = 0; j < 4; ++j) {
    ap[j] = *(const half8*)(Ap + j * 8);
    bp[j] = *(const half8*)(Bp + j * 8);
  }

  for (int k0 = 0; k0 < K; k0 += GBK) {
    __syncthreads();
#pragma unroll
    for (int j = 0; j < 4; ++j) {
      *(half8*)(&As[srow][scol + j * 8]) = ap[j];
      *(half8*)(&Bs[srow][scol + j * 8]) = bp[j];
    }
    __syncthreads();
    if (k0 + GBK < K) {
      const int kn = k0 + GBK;
#pragma unroll
      for (int j = 0; j < 4; ++j) {
        ap[j] = *(const half8*)(Ap + kn + j * 8);
        bp[j] = *(const half8*)(Bp + kn + j * 8);
      }
    }
#pragma unroll
    for (int kc = 0; kc < 2; ++kc) {
      half8 af[4], bf[4];
#pragma unroll
      for (int i = 0; i < 4; ++i)
        af[i] = *(const half8*)(&As[wr * 64 + i * 16 + l16][kc * 32 + quad * 8]);
#pragma unroll
      for (int j = 0; j < 4; ++j)
        bf[j] = *(const half8*)(&Bs[wc * 64 + j * 16 + l16][kc * 32 + quad * 8]);
#pragma unroll
      for (int i = 0; i < 4; ++i)
#pragma unroll
        for (int j = 0; j < 4; ++j)
          acc[i][j] = __builtin_amdgcn_mfma_f32_16x16x32_f16(af[i], bf[j], acc[i][j], 0, 0, 0);
    }
  }

#pragma unroll
  for (int j = 0; j < 4; ++j) {
    const int col = bn + wc * 64 + j * 16 + l16;
    const float bv = bias ? bias[col] : 0.f;
#pragma unroll
    for (int i = 0; i < 4; ++i) {
      const int row0 = bm + wr * 64 + i * 16 + quad * 4;
#pragma unroll
      for (int r = 0; r < 4; ++r)
        C[(size_t)(row0 + r) * N + col] = acc[i][j][r] + bv;
    }
  }
}

// ---------------------------------------------------------------------------
// R17 split-K2 GEMM for the down projection (neutral vs single-K, kept).
// ---------------------------------------------------------------------------
__global__ __launch_bounds__(256) void gemm_h16_sk(
    const _Float16* __restrict__ A, const _Float16* __restrict__ B,
    float* __restrict__ C0, float* __restrict__ C1,
    int M, int N, int Kfull, int Ksp)
{
  __shared__ __align__(16) _Float16 As[GBM][LDKG];
  __shared__ __align__(16) _Float16 Bs[GBN][LDKG];
  const int tid = threadIdx.x;
  const int lane = tid & 63, w = tid >> 6;
  const int wr = w >> 1, wc = w & 1;
  const int quad = lane >> 4, l16 = lane & 15;
  const int bm = blockIdx.y * GBM, bn = blockIdx.x * GBN;
  float* C = blockIdx.z ? C1 : C0;
  const size_t koff = (size_t)blockIdx.z * Ksp;
  const int srow = tid >> 1;
  const int scol = (tid & 1) * 32;

  v4f acc[4][4];
#pragma unroll
  for (int i = 0; i < 4; ++i)
#pragma unroll
    for (int j = 0; j < 4; ++j) acc[i][j] = (v4f){0.f, 0.f, 0.f, 0.f};

  const _Float16* Ap = A + (size_t)(bm + srow) * Kfull + koff + scol;
  const _Float16* Bp = B + (size_t)(bn + srow) * Kfull + koff + scol;
  half8 ap[4], bp[4];
#pragma unroll
  for (int j = 0; j < 4; ++j) {
    ap[j] = *(const half8*)(Ap + j * 8);
    bp[j] = *(const half8*)(Bp + j * 8);
  }

  for (int k0 = 0; k0 < Ksp; k0 += GBK) {
    __syncthreads();
#pragma unroll
    for (int j = 0; j < 4; ++j) {
      *(half8*)(&As[srow][scol + j * 8]) = ap[j];
      *(half8*)(&Bs[srow][scol + j * 8]) = bp[j];
    }
    __syncthreads();
    if (k0 + GBK < Ksp) {
      const int kn = k0 + GBK;
#pragma unroll
      for (int j = 0; j < 4; ++j) {
        ap[j] = *(const half8*)(Ap + kn + j * 8);
        bp[j] = *(const half8*)(Bp + kn + j * 8);
      }
    }
#pragma unroll
    for (int kc = 0; kc < 2; ++kc) {
      half8 af[4], bf[4];
#pragma unroll
      for (int i = 0; i < 4; ++i)
        af[i] = *(const half8*)(&As[wr * 64 + i * 16 + l16][kc * 32 + quad * 8]);
#pragma unroll
      for (int j = 0; j < 4; ++j)
        bf[j] = *(const half8*)(&Bs[wc * 64 + j * 16 + l16][kc * 32 + quad * 8]);
#pragma unroll
      for (int i = 0; i < 4; ++i)
#pragma unroll
        for (int j = 0; j < 4; ++j)
          acc[i][j] = __builtin_amdgcn_mfma_f32_16x16x32_f16(af[i], bf[j], acc[i][j], 0, 0, 0);
    }
  }

#pragma unroll
  for (int j = 0; j < 4; ++j) {
    const int col = bn + wc * 64 + j * 16 + l16;
#pragma unroll
    for (int i = 0; i < 4; ++i) {
      const int row0 = bm + wr * 64 + i * 16 + quad * 4;
#pragma unroll
      for (int r = 0; r < 4; ++r)
        C[(size_t)(row0 + r) * N + col] = acc[i][j][r];
    }
  }
}

// ---------------------------------------------------------------------------
// Up-projection GEMM (BK=64): writes x_m half as f16 (xmh), silu(z) f16 (szb).
// ---------------------------------------------------------------------------
__global__ __launch_bounds__(256) void gemm_h16_up(
    const _Float16* __restrict__ A, const _Float16* __restrict__ B,
    _Float16* __restrict__ xmh, _Float16* __restrict__ szb,
    int M, int N, int K)
{
  __shared__ __align__(16) _Float16 As[GBM][LDKG];
  __shared__ __align__(16) _Float16 Bs[GBN][LDKG];
  const int tid = threadIdx.x;
  const int lane = tid & 63, w = tid >> 6;
  const int wr = w >> 1, wc = w & 1;
  const int quad = lane >> 4, l16 = lane & 15;
  const int bm = blockIdx.y * GBM, bn = blockIdx.x * GBN;
  const int srow = tid >> 1;
  const int scol = (tid & 1) * 32;

  v4f acc[4][4];
#pragma unroll
  for (int i = 0; i < 4; ++i)
#pragma unroll
    for (int j = 0; j < 4; ++j) acc[i][j] = (v4f){0.f, 0.f, 0.f, 0.f};

  const _Float16* Ap = A + (size_t)(bm + srow) * K + scol;
  const _Float16* Bp = B + (size_t)(bn + srow) * K + scol;
  half8 ap[4], bp[4];
#pragma unroll
  for (int j = 0; j < 4; ++j) {
    ap[j] = *(const half8*)(Ap + j * 8);
    bp[j] = *(const half8*)(Bp + j * 8);
  }

  for (int k0 = 0; k0 < K; k0 += GBK) {
    __syncthreads();
#pragma unroll
    for (int j = 0; j < 4; ++j) {
      *(half8*)(&As[srow][scol + j * 8]) = ap[j];
      *(half8*)(&Bs[srow][scol + j * 8]) = bp[j];
    }
    __syncthreads();
    if (k0 + GBK < K) {
      const int kn = k0 + GBK;
#pragma unroll
      for (int j = 0; j < 4; ++j) {
        ap[j] = *(const half8*)(Ap + kn + j * 8);
        bp[j] = *(const half8*)(Bp + kn + j * 8);
      }
    }
#pragma unroll
    for (int kc = 0; kc < 2; ++kc) {
      half8 af[4], bf[4];
#pragma unroll
      for (int i = 0; i < 4; ++i)
        af[i] = *(const half8*)(&As[wr * 64 + i * 16 + l16][kc * 32 + quad * 8]);
#pragma unroll
      for (int j = 0; j < 4; ++j)
        bf[j] = *(const half8*)(&Bs[wc * 64 + j * 16 + l16][kc * 32 + quad * 8]);
#pragma unroll
      for (int i = 0; i < 4; ++i)
#pragma unroll
        for (int j = 0; j < 4; ++j)
          acc[i][j] = __builtin_amdgcn_mfma_f32_16x16x32_f16(af[i], bf[j], acc[i][j], 0, 0, 0);
    }
  }

  const bool zhalf = (bn >= INNER_D);
#pragma unroll
  for (int j = 0; j < 4; ++j) {
    const int col = bn + wc * 64 + j * 16 + l16;
    const int colm = col & (INNER_D - 1);
#pragma unroll
    for (int i = 0; i < 4; ++i) {
      const int row0 = bm + wr * 64 + i * 16 + quad * 4;
#pragma unroll
      for (int r = 0; r < 4; ++r) {
        float a = acc[i][j][r];
        if (zhalf) {
          float s = a / (1.f + __expf(-a));
          szb[(size_t)(row0 + r) * INNER_D + colm] = (_Float16)s;
        } else {
          xmh[(size_t)(row0 + r) * INNER_D + colm] = (_Float16)a;
        }
      }
    }
  }
}

// ---------------------------------------------------------------------------
__device__ __forceinline__ float block_sum4(float v, float* red, int tid) {
#pragma unroll
  for (int off = 32; off; off >>= 1) v += __shfl_xor(v, off);
  if ((tid & 63) == 0) red[tid >> 6] = v;
  __syncthreads();
  float t = red[0] + red[1] + red[2] + red[3];
  __syncthreads();
  return t;
}

// ---------------------------------------------------------------------------
// R19: ln_mul + W_up cast in one dispatch.
// ---------------------------------------------------------------------------
__global__ __launch_bounds__(256) void ln_mul_castwup_kernel(
    const float* __restrict__ in, const float* __restrict__ w,
    _Float16* __restrict__ out,
    const float* __restrict__ wup_src, _Float16* __restrict__ wup_dst,
    int nwup, int ncast)
{
  __shared__ float red[4];
  const int tid = threadIdx.x;
  if ((int)blockIdx.x < ncast) {
    int i = (blockIdx.x * 256 + tid) * 4;
    if (i < nwup) {
      float4 v = *(const float4*)(wup_src + i);
      half4_t o = {(_Float16)v.x, (_Float16)v.y, (_Float16)v.z, (_Float16)v.w};
      *(half4_t*)(wup_dst + i) = o;
    }
    return;
  }
  const int row = blockIdx.x - ncast;
  const float* p = in + (size_t)row * E_DIM;
  float v0 = p[tid], v1 = p[tid + 256];
  float mean = block_sum4(v0 + v1, red, tid) * (1.f / E_DIM);
  float d0 = v0 - mean, d1 = v1 - mean;
  float var = block_sum4(d0 * d0 + d1 * d1, red, tid) * (1.f / E_DIM);
  float rstd = rsqrtf(var + 1e-5f);
  out[(size_t)row * E_DIM + tid] = (_Float16)(d0 * rstd * w[tid]);
  out[(size_t)row * E_DIM + tid + 256] = (_Float16)(d1 * rstd * w[tid + 256]);
}

// final_ln: out = LN(res + y1 + y2) * w   (y2 from split-K partial)
__global__ __launch_bounds__(256) void final_ln_kernel(
    const float* __restrict__ res, const float* __restrict__ y1,
    const float* __restrict__ y2,
    const float* __restrict__ w, float* __restrict__ out)
{
  __shared__ float red[4];
  const int row = blockIdx.x;
  const int tid = threadIdx.x;
  const size_t base = (size_t)row * E_DIM;
  float v0 = res[base + tid] + y1[base + tid] + y2[base + tid];
  float v1 = res[base + tid + 256] + y1[base + tid + 256] + y2[base + tid + 256];
  float mean = block_sum4(v0 + v1, red, tid) * (1.f / E_DIM);
  float d0 = v0 - mean, d1 = v1 - mean;
  float var = block_sum4(d0 * d0 + d1 * d1, red, tid) * (1.f / E_DIM);
  float rstd = rsqrtf(var + 1e-5f);
  out[base + tid] = d0 * rstd * w[tid];
  out[base + tid + 256] = d1 * rstd * w[tid + 256];
}

// ---------------------------------------------------------------------------
// Fused conv+silu + headwise q/k/v + gates, 4 rows per block.
// ---------------------------------------------------------------------------
__global__ __launch_bounds__(256) void chg_kernel(
    const _Float16* __restrict__ xm, const float* __restrict__ cw,
    const float* __restrict__ cb,
    const float* __restrict__ Wq, const float* __restrict__ Wk,
    const float* __restrict__ Wv,
    const float* __restrict__ Wig, const float* __restrict__ big,
    const float* __restrict__ Wfg, const float* __restrict__ bfg,
    _Float16* __restrict__ xch, _Float16* __restrict__ qh,
    _Float16* __restrict__ khb, _Float16* __restrict__ vhb,
    float* __restrict__ ig, float* __restrict__ fg)
{
  __shared__ float red[4][32];
  const int tid = threadIdx.x;
  const int lane = tid & 63, wid = tid >> 6;
  const int row0 = blockIdx.x * 4;
  const int sl0 = row0 & (S_LEN - 1);
  const int c = tid * 4;

  float t[7][4];
#pragma unroll
  for (int j = 0; j < 7; ++j) {
    const int off = j - 3;
    if (sl0 + off < 0) {
      t[j][0] = t[j][1] = t[j][2] = t[j][3] = 0.f;
    } else {
      half4_t hv = *(const half4_t*)(xm + (size_t)(row0 + off) * INNER_D + c);
      t[j][0] = (float)hv.x; t[j][1] = (float)hv.y;
      t[j][2] = (float)hv.z; t[j][3] = (float)hv.w;
    }
  }
  float wct[4][4];
#pragma unroll
  for (int j = 0; j < 4; ++j) {
    float4 wc4 = *(const float4*)(cw + (c + j) * 4);
    wct[j][0] = wc4.x; wct[j][1] = wc4.y; wct[j][2] = wc4.z; wct[j][3] = wc4.w;
  }
  float4 cb4 = *(const float4*)(cb + c);
  const float cbs[4] = {cb4.x, cb4.y, cb4.z, cb4.w};
  float wqm[16], wkm[16], wvm[16];
#pragma unroll
  for (int i = 0; i < 4; ++i) {
    float4 a = *(const float4*)(Wq + tid * 16 + i * 4);
    float4 bq = *(const float4*)(Wk + tid * 16 + i * 4);
    float4 cq = *(const float4*)(Wv + tid * 16 + i * 4);
    wqm[i * 4] = a.x; wqm[i * 4 + 1] = a.y; wqm[i * 4 + 2] = a.z; wqm[i * 4 + 3] = a.w;
    wkm[i * 4] = bq.x; wkm[i * 4 + 1] = bq.y; wkm[i * 4 + 2] = bq.z; wkm[i * 4 + 3] = bq.w;
    wvm[i * 4] = cq.x; wvm[i * 4 + 1] = cq.y; wvm[i * 4 + 2] = cq.z; wvm[i * 4 + 3] = cq.w;
  }

  float q4[4][4], k4[4][4], v4m[4][4];
#pragma unroll
  for (int r = 0; r < 4; ++r) {
    float xc4[4];
#pragma unroll
    for (int j = 0; j < 4; ++j) {
      float a = cbs[j] + wct[j][0] * t[r][j] + wct[j][1] * t[r + 1][j]
                       + wct[j][2] * t[r + 2][j] + wct[j][3] * t[r + 3][j];
      xc4[j] = a / (1.f + __expf(-a));
    }
#pragma unroll
    for (int i = 0; i < 4; ++i) {
      q4[r][i] = wqm[i * 4] * xc4[0] + wqm[i * 4 + 1] * xc4[1]
               + wqm[i * 4 + 2] * xc4[2] + wqm[i * 4 + 3] * xc4[3];
      k4[r][i] = wkm[i * 4] * xc4[0] + wkm[i * 4 + 1] * xc4[1]
               + wkm[i * 4 + 2] * xc4[2] + wkm[i * 4 + 3] * xc4[3];
      v4m[r][i] = wvm[i * 4] * t[r + 3][0] + wvm[i * 4 + 1] * t[r + 3][1]
                + wvm[i * 4 + 2] * t[r + 3][2] + wvm[i * 4 + 3] * t[r + 3][3];
    }
    const size_t base = (size_t)(row0 + r) * INNER_D + c;
    half4_t xo = {(_Float16)xc4[0], (_Float16)xc4[1], (_Float16)xc4[2], (_Float16)xc4[3]};
    half4_t qo = {(_Float16)q4[r][0], (_Float16)q4[r][1], (_Float16)q4[r][2], (_Float16)q4[r][3]};
    half4_t ko = {(_Float16)k4[r][0], (_Float16)k4[r][1], (_Float16)k4[r][2], (_Float16)k4[r][3]};
    half4_t vo = {(_Float16)v4m[r][0], (_Float16)v4m[r][1], (_Float16)v4m[r][2], (_Float16)v4m[r][3]};
    *(half4_t*)(xch + base) = xo;
    *(half4_t*)(qh + base) = qo;
    *(half4_t*)(khb + base) = ko;
    *(half4_t*)(vhb + base) = vo;
  }

  float vals[32];
#pragma unroll
  for (int g = 0; g < 8; ++g) {
    const float* wb = (g < 4 ? Wig : Wfg) + (g & 3) * 3072 + c;
    float4 w1 = *(const float4*)(wb);
    float4 w2 = *(const float4*)(wb + 1024);
    float4 w3 = *(const float4*)(wb + 2048);
#pragma unroll
    for (int r = 0; r < 4; ++r) {
      vals[g * 4 + r] =
          q4[r][0] * w1.x + q4[r][1] * w1.y + q4[r][2] * w1.z + q4[r][3] * w1.w
        + k4[r][0] * w2.x + k4[r][1] * w2.y + k4[r][2] * w2.z + k4[r][3] * w2.w
        + v4m[r][0] * w3.x + v4m[r][1] * w3.y + v4m[r][2] * w3.z + v4m[r][3] * w3.w;
    }
  }
#pragma unroll
  for (int i = 0; i < 32; ++i) {
    float x = vals[i];
#pragma unroll
    for (int off = 32; off; off >>= 1) x += __shfl_xor(x, off);
    vals[i] = x;
  }
  if (lane == 0) {
#pragma unroll
    for (int i = 0; i < 32; ++i) red[wid][i] = vals[i];
  }
  __syncthreads();
  if (tid < 32) {
    float sm = red[0][tid] + red[1][tid] + red[2][tid] + red[3][tid];
    const int g = tid >> 2, r = tid & 3;
    const int h = g & 3;
    const int b = row0 >> 10;
    const size_t oidx = (size_t)(b * NH_D + h) * S_LEN + sl0 + r;
    if (g < 4) ig[oidx] = sm + big[h];
    else       fg[oidx] = sm + bfg[h];
  }
}

// ---------------------------------------------------------------------------
__device__ __forceinline__ float logsigf(float x) {
  return fminf(x, 0.f) - log1pf(__expf(-fabsf(x)));
}

// ---------------------------------------------------------------------------
// R18 merged scan + vtrans + R19 W_down cast tail.
// Blocks 0-31 scan; 32..2079 vtrans; 2080.. cast W_down.
// ---------------------------------------------------------------------------
__global__ __launch_bounds__(256) void scan_vtrans_kernel(
    const float* __restrict__ ig, const float* __restrict__ fg,
    float* __restrict__ m_, float* __restrict__ rmax_, float* __restrict__ maxd_,
    float* __restrict__ em_,
    const _Float16* __restrict__ vb, _Float16* __restrict__ vt,
    const float* __restrict__ wdn_src, _Float16* __restrict__ wdn_dst,
    int nwdn)
{
  __shared__ float sc[256];
  __shared__ _Float16 tile[64][68];
  const int tid = threadIdx.x;

  if (blockIdx.x < 32) {
    // ---- scan body (bh = blockIdx.x) ----
    const int bh = blockIdx.x;
    const size_t base = (size_t)bh * S_LEN + tid * 4;
    float4 f4 = *(const float4*)(fg + base);
    float4 i4 = *(const float4*)(ig + base);
    float l0 = logsigf(f4.x), l1 = logsigf(f4.y), l2 = logsigf(f4.z), l3 = logsigf(f4.w);
    float p0 = l0, p1 = p0 + l1, p2 = p1 + l2, p3 = p2 + l3;
    sc[tid] = p3;
    __syncthreads();
    for (int off = 1; off < 256; off <<= 1) {
      float o = (tid >= off) ? sc[tid - off] : 0.f;
      __syncthreads();
      sc[tid] += o;
      __syncthreads();
    }
    float aoff = (tid == 0) ? 0.f : sc[tid - 1];
    __syncthreads();
    float a0 = aoff + p0, a1 = aoff + p1, a2 = aoff + p2, a3 = aoff + p3;
    float m0 = i4.x - a0, m1 = i4.y - a1, m2 = i4.z - a2, m3 = i4.w - a3;
    float x0 = m0, x1 = fmaxf(x0, m1), x2 = fmaxf(x1, m2), x3 = fmaxf(x2, m3);
    sc[tid] = x3;
    __syncthreads();
    for (int off = 1; off < 256; off <<= 1) {
      float o = (tid >= off) ? sc[tid - off] : -1e30f;
      __syncthreads();
      sc[tid] = fmaxf(sc[tid], o);
      __syncthreads();
    }
    float moff = (tid == 0) ? -1e30f : sc[tid - 1];
    float tmax = sc[tid | 15];
    float r0 = fmaxf(moff, x0), r1 = fmaxf(moff, x1), r2 = fmaxf(moff, x2), r3 = fmaxf(moff, x3);
    const float scale = 0.0625f;
    float4 mo = {m0, m1, m2, m3};
    float4 ro = {r0, r1, r2, r3};
    float4 dd = {a0 + r0, a1 + r1, a2 + r2, a3 + r3};
    float4 eo = {scale * __expf(m0 - tmax), scale * __expf(m1 - tmax),
                 scale * __expf(m2 - tmax), scale * __expf(m3 - tmax)};
    *(float4*)(m_ + base) = mo;
    *(float4*)(rmax_ + base) = ro;
    *(float4*)(maxd_ + base) = dd;
    *(float4*)(em_ + base) = eo;
    return;
  }

  if (blockIdx.x >= 32 + 2048) {
    // ---- W_down cast tail ----
    int i = ((blockIdx.x - 32 - 2048) * 256 + tid) * 4;
    if (i < nwdn) {
      float4 v = *(const float4*)(wdn_src + i);
      half4_t o = {(_Float16)v.x, (_Float16)v.y, (_Float16)v.z, (_Float16)v.w};
      *(half4_t*)(wdn_dst + i) = o;
    }
    return;
  }

  // ---- vtrans body ----
  const int vbid = blockIdx.x - 32;
  const int dt = vbid & 15, st = (vbid >> 4) & 15, b = vbid >> 8;
  const int c4 = (tid & 15) * 4, rr = tid >> 4;
  const int s0 = st * 64, d0 = dt * 64;
#pragma unroll
  for (int i = 0; i < 4; ++i) {
    int r = rr + i * 16;
    half4_t v = *(const half4_t*)(vb + ((size_t)(b * S_LEN + s0 + r)) * INNER_D + d0 + c4);
    tile[r][c4 + 0] = v.x; tile[r][c4 + 1] = v.y;
    tile[r][c4 + 2] = v.z; tile[r][c4 + 3] = v.w;
  }
  __syncthreads();
#pragma unroll
  for (int i = 0; i < 4; ++i) {
    int dd = rr + i * 16;
    half4_t o = {tile[c4 + 0][dd], tile[c4 + 1][dd], tile[c4 + 2][dd], tile[c4 + 3][dd]};
    *(half4_t*)(vt + ((size_t)(b * INNER_D + d0 + dd)) * S_LEN + s0 + c4) = o;
  }
}

// ---------------------------------------------------------------------------
// R20: R16 shell (uniform pairing, XCD mapping, shared 512-thread staging)
// + R8 compute split (each wave owns 16 rows x ALL 64 keys -> P is
// WAVE-PRIVATE). Removes the mid-tile P-visibility barrier: 3 -> 2 block
// barriers per tile (P round-trip fenced by a wave-local lgkmcnt(0), the
// verified R8 pattern). Epilogue cross-wave cred reductions collapse to
// in-wave shuffles. Cost: K/V fragment reuse 2x -> 1x (+~36 b128/tile/wave
// ~= 430cy at ds throughput, small vs ~11k-cycle measured tile latency).
// ---------------------------------------------------------------------------
#define KP 264
#define VP 72

__global__ __launch_bounds__(512, 1) void attn_blk_kernel(
    const _Float16* __restrict__ qh, const _Float16* __restrict__ khb,
    const _Float16* __restrict__ vt,
    const float* __restrict__ m_, const float* __restrict__ em,
    const float* __restrict__ rmax_, const float* __restrict__ maxd_,
    const float* __restrict__ mhln_w, const float* __restrict__ skip,
    const _Float16* __restrict__ xch, const _Float16* __restrict__ szb,
    _Float16* __restrict__ hstate)
{
  __shared__ __align__(16) _Float16 Ks[64][KP];
  __shared__ __align__(16) _Float16 Vs[256][VP];
  __shared__ __align__(16) _Float16 plds[8][16][72];
  const int tid = threadIdx.x;
  const int lane = tid & 63, wid = tid >> 6;      // wid 0..7
  const int quad = lane >> 4, l16 = lane & 15;
  const int grp = wid >> 2;          // 0 = long q-block, 1 = short q-block
  const int widg = wid & 3;          // row-quarter within group (16 rows)
  const int bh = blockIdx.x & 31;    // XCD-local: same bh -> bid stride 32
  const int j = blockIdx.x >> 5;     // pair index 0..7
  const int qblk = grp ? j : (15 - j);
  const int ntile = qblk + 1;        // this group's k-tiles
  const int Tmax = 16 - j;           // block loop count (= long group's ntile)
  const int qb0 = qblk * 64;
  const int s0 = qb0 + widg * 16;    // this wave's 16 q-rows
  const int h = bh & 3, b = bh >> 2;
  _Float16 (*P)[72] = plds[wid];
  const float* rmaxp = rmax_ + (size_t)bh * S_LEN;
  const float* emp = em + (size_t)bh * S_LEN;
  const float* mp = m_ + (size_t)bh * S_LEN;
  const float* maxdp = maxd_ + (size_t)bh * S_LEN;
  const float scale = 0.0625f;

  const _Float16* kg = khb + ((size_t)(b * S_LEN)) * INNER_D + h * DH_D;
  const _Float16* vg = vt + ((size_t)(b * INNER_D + h * DH_D)) * S_LEN;
  // staging split over 512 threads: 4 half8 K + 4 half8 V per thread
  const int krow_s = tid >> 5;          // 0..15
  const int kcol_s = (tid & 31) * 8;    // 0..248
  const int vrow_s = tid >> 3;          // 0..63
  const int vcol_s = (tid & 7) * 8;     // 0..56

  half8 kpre[4], vpre[4];
#pragma unroll
  for (int i = 0; i < 4; ++i) {
    kpre[i] = *(const half8*)(kg + (size_t)(i * 16 + krow_s) * INNER_D + kcol_s);
    vpre[i] = *(const half8*)(vg + (size_t)(i * 64 + vrow_s) * S_LEN + vcol_s);
  }

  // Q fragments for this wave's 16 rows.
  half8 qf[8];
  const _Float16* qrow = qh + ((size_t)(b * S_LEN + s0 + l16)) * INNER_D + h * DH_D + quad * 8;
#pragma unroll
  for (int c = 0; c < 8; ++c) qf[c] = *(const half8*)(qrow + c * 32);

  v4f acc[16];
#pragma unroll
  for (int nc = 0; nc < 16; ++nc) acc[nc] = (v4f){0.f, 0.f, 0.f, 0.f};
  float rsum[4] = {0.f, 0.f, 0.f, 0.f};
  float rmax_row[4];
#pragma unroll
  for (int r = 0; r < 4; ++r) rmax_row[r] = rmaxp[s0 + quad * 4 + r];

  for (int tt = 0; tt < Tmax; ++tt) {
    const int t0 = tt * 64;
    const bool active = (tt < ntile);
    const bool diag = (tt == ntile - 1);
    __syncthreads();
#pragma unroll
    for (int i = 0; i < 4; ++i) {
      *(half8*)(&Ks[i * 16 + krow_s][kcol_s]) = kpre[i];
      *(half8*)(&Vs[i * 64 + vrow_s][vcol_s]) = vpre[i];
    }
    __syncthreads();
    if (tt + 1 < Tmax) {
      const int tn = t0 + 64;
#pragma unroll
      for (int i = 0; i < 4; ++i) {
        kpre[i] = *(const half8*)(kg + (size_t)(tn + i * 16 + krow_s) * INNER_D + kcol_s);
        vpre[i] = *(const half8*)(vg + (size_t)(i * 64 + vrow_s) * S_LEN + tn + vcol_s);
      }
    }
    if (active) {
      float rowfac[4];
      if (!diag) {
        const float rtile = rmaxp[t0 + 63];
#pragma unroll
        for (int r = 0; r < 4; ++r) rowfac[r] = __expf(rtile - rmax_row[r]);
      }
      // ---- QK^T: 16 rows x all 64 keys (4 key-subtiles), wave-private.
#pragma unroll
      for (int sub = 0; sub < 4; ++sub) {
        v4f sacc0 = (v4f){0.f, 0.f, 0.f, 0.f};
        v4f sacc1 = (v4f){0.f, 0.f, 0.f, 0.f};
#pragma unroll
        for (int c = 0; c < 4; ++c) {
          half8 kf0 = *(const half8*)(&Ks[sub * 16 + l16][c * 32 + quad * 8]);
          half8 kf1 = *(const half8*)(&Ks[sub * 16 + l16][(c + 4) * 32 + quad * 8]);
          sacc0 = __builtin_amdgcn_mfma_f32_16x16x32_f16(qf[c], kf0, sacc0, 0, 0, 0);
          sacc1 = __builtin_amdgcn_mfma_f32_16x16x32_f16(qf[c + 4], kf1, sacc1, 0, 0, 0);
        }
        v4f sacc = sacc0 + sacc1;
        const int t = t0 + sub * 16 + l16;
        if (diag) {
          const float mt = mp[t];
#pragma unroll
          for (int r = 0; r < 4; ++r) {
            const int srow = s0 + quad * 4 + r;
            float cc = (t <= srow) ? sacc[r] * scale * __expf(mt - rmax_row[r]) : 0.f;
            rsum[r] += cc;
            P[quad * 4 + r][sub * 16 + l16] = (_Float16)cc;
          }
        } else {
          const float emv = emp[t];
#pragma unroll
          for (int r = 0; r < 4; ++r) {
            float cc = sacc[r] * emv * rowfac[r];
            rsum[r] += cc;
            P[quad * 4 + r][sub * 16 + l16] = (_Float16)cc;
          }
        }
      }
      // wave-local P round-trip fence (R8 pattern) — no block barrier.
      asm volatile("s_waitcnt lgkmcnt(0)" ::: "memory");
      half8 pf0 = *(const half8*)(&P[l16][quad * 8]);
      half8 pf1 = *(const half8*)(&P[l16][32 + quad * 8]);
#pragma unroll
      for (int nc = 0; nc < 16; ++nc) {
        half8 vf0 = *(const half8*)(&Vs[nc * 16 + l16][quad * 8]);
        half8 vf1 = *(const half8*)(&Vs[nc * 16 + l16][32 + quad * 8]);
        acc[nc] = __builtin_amdgcn_mfma_f32_16x16x32_f16(pf0, vf0, acc[nc], 0, 0, 0);
        acc[nc] = __builtin_amdgcn_mfma_f32_16x16x32_f16(pf1, vf1, acc[nc], 0, 0, 0);
      }
    }
  }

  // ---- epilogue: all reductions wave-local (16 rows owned end-to-end).
  float inv[4];
#pragma unroll
  for (int r = 0; r < 4; ++r) {
    float rs = rsum[r];
    rs += __shfl_xor(rs, 1); rs += __shfl_xor(rs, 2);
    rs += __shfl_xor(rs, 4); rs += __shfl_xor(rs, 8);
    float md = maxdp[s0 + quad * 4 + r];
    float n = fmaxf(fabsf(rs), __expf(-md));
    inv[r] = 1.f / (n + 1e-6f);
  }
#pragma unroll
  for (int nc = 0; nc < 16; ++nc) {
#pragma unroll
    for (int r = 0; r < 4; ++r) acc[nc][r] *= inv[r];
  }
  float mean[4], rstd[4];
#pragma unroll
  for (int r = 0; r < 4; ++r) {
    float sm = 0.f;
#pragma unroll
    for (int nc = 0; nc < 16; ++nc) sm += acc[nc][r];
    sm += __shfl_xor(sm, 1); sm += __shfl_xor(sm, 2);
    sm += __shfl_xor(sm, 4); sm += __shfl_xor(sm, 8);
    mean[r] = sm * (1.f / DH_D);
  }
#pragma unroll
  for (int r = 0; r < 4; ++r) {
    float sq = 0.f;
#pragma unroll
    for (int nc = 0; nc < 16; ++nc) { float d = acc[nc][r] - mean[r]; sq += d * d; }
    sq += __shfl_xor(sq, 1); sq += __shfl_xor(sq, 2);
    sq += __shfl_xor(sq, 4); sq += __shfl_xor(sq, 8);
    rstd[r] = rsqrtf(sq * (1.f / DH_D) + 1e-5f);
  }
#pragma unroll
  for (int nc = 0; nc < 16; ++nc) {
    const int d = h * DH_D + nc * 16 + l16;
    const float w = mhln_w[d];
    const float sk = skip[d];
#pragma unroll
    for (int r = 0; r < 4; ++r) {
      const size_t row = (size_t)(b * S_LEN + s0 + quad * 4 + r);
      float xcv = (float)xch[row * INNER_D + d];
      float sz = (float)szb[row * INNER_D + d];
      float o = ((acc[nc][r] - mean[r]) * rstd[r] * w + sk * xcv) * sz;
      hstate[row * INNER_D + d] = (_Float16)o;
    }
  }
}

// ---------------------------------------------------------------------------
extern "C" void kernel_launch(void* const* d_in, const int* in_sizes, int n_in,
                              void* d_out, int out_size, void* d_ws, size_t ws_size,
                              hipStream_t stream)
{
  const float* x      = (const float*)d_in[0];
  const float* W_in   = (const float*)d_in[1];
  const float* b_in   = (const float*)d_in[2];
  const float* ln1_w  = (const float*)d_in[3];
  const float* W_up   = (const float*)d_in[4];
  const float* conv_w = (const float*)d_in[5];
  const float* conv_b = (const float*)d_in[6];
  const float* Wq     = (const float*)d_in[7];
  const float* Wk     = (const float*)d_in[8];
  const float* Wv     = (const float*)d_in[9];
  const float* W_ig   = (const float*)d_in[10];
  const float* b_ig   = (const float*)d_in[11];
  const float* W_fg   = (const float*)d_in[12];
  const float* b_fg   = (const float*)d_in[13];
  const float* mhln_w = (const float*)d_in[14];
  const float* skip   = (const float*)d_in[15];
  const float* W_down = (const float*)d_in[16];
  const float* ln_post_w = (const float*)d_in[17];
  float* out = (float*)d_out;

  float* ws = (float*)d_ws;
  size_t o = 0;
  float* xp     = ws + o; o += (size_t)NROW * E_DIM;
  float* hbuf   = ws + o; o += (size_t)NROW * E_DIM;
  _Float16* h16 = (_Float16*)(ws + o);
  size_t ho = 0;
  _Float16* xh      = h16 + ho; ho += (size_t)NROW * F_IN_D;
  _Float16* WinH    = h16 + ho; ho += (size_t)E_DIM * F_IN_D;
  _Float16* WupH    = h16 + ho; ho += (size_t)2 * INNER_D * E_DIM;
  _Float16* WdownH  = h16 + ho; ho += (size_t)E_DIM * INNER_D;
  _Float16* hh      = h16 + ho; ho += (size_t)NROW * E_DIM;
  _Float16* xmh     = h16 + ho; ho += (size_t)NROW * INNER_D;
  _Float16* szb     = h16 + ho; ho += (size_t)NROW * INNER_D;
  _Float16* xch     = h16 + ho; ho += (size_t)NROW * INNER_D;
  _Float16* qh      = h16 + ho; ho += (size_t)NROW * INNER_D;
  _Float16* khb     = h16 + ho; ho += (size_t)NROW * INNER_D;
  _Float16* vhb     = h16 + ho; ho += (size_t)NROW * INNER_D;
  _Float16* vtb     = h16 + ho; ho += (size_t)NROW * INNER_D;
  _Float16* hstateH = h16 + ho; ho += (size_t)NROW * INNER_D;

  const int GSZ = B_SZ * NH_D * S_LEN;  // 32768
  float* igb   = hbuf;
  float* fgb   = hbuf + GSZ;
  float* mb    = hbuf + 2 * GSZ;
  float* rmaxb = hbuf + 3 * GSZ;
  float* maxdb = hbuf + 4 * GSZ;
  float* emb   = hbuf + 5 * GSZ;
  // split-K partials reuse qh/khb (dead after attention).
  float* yb1 = (float*)qh;
  float* yb2 = (float*)khb;

  dim3 blk(256);
  const int nx = NROW * F_IN_D;                // 2,097,152
  const int nwi = E_DIM * F_IN_D;              //   131,072
  const int nwu = 2 * INNER_D * E_DIM;         // 1,048,576
  const int nwd = E_DIM * INNER_D;             //   524,288
  const int ncast_up = nwu / 4 / 256;          // 1024 blocks
  const int ncast_dn = nwd / 4 / 256;          //  512 blocks

  cast2_kernel<<<(nx + nwi) / 4 / 256, blk, 0, stream>>>(
      x, W_in, xh, WinH, nx, nwi);
  gemm_h16<<<dim3(E_DIM / GBN, NROW / GBM), blk, 0, stream>>>(
      xh, WinH, b_in, xp, NROW, E_DIM, F_IN_D);
  ln_mul_castwup_kernel<<<ncast_up + NROW, blk, 0, stream>>>(
      xp, ln1_w, hh, W_up, WupH, nwu, ncast_up);
  gemm_h16_up<<<dim3(2 * INNER_D / GBN, NROW / GBM), blk, 0, stream>>>(
      hh, WupH, xmh, szb, NROW, 2 * INNER_D, E_DIM);
  chg_kernel<<<NROW / 4, blk, 0, stream>>>(
      xmh, conv_w, conv_b, Wq, Wk, Wv, W_ig, b_ig, W_fg, b_fg,
      xch, qh, khb, vhb, igb, fgb);
  scan_vtrans_kernel<<<32 + 2048 + ncast_dn, blk, 0, stream>>>(
      igb, fgb, mb, rmaxb, maxdb, emb, vhb, vtb, W_down, WdownH, nwd);
  attn_blk_kernel<<<256, dim3(512), 0, stream>>>(
      qh, khb, vtb, mb, emb, rmaxb, maxdb, mhln_w, skip, xch, szb, hstateH);
  gemm_h16_sk<<<dim3(E_DIM / GBN, NROW / GBM, 2), blk, 0, stream>>>(
      hstateH, WdownH, yb1, yb2, NROW, E_DIM, INNER_D, INNER_D / 2);
  final_ln_kernel<<<NROW, blk, 0, stream>>>(xp, yb1, yb2, ln_post_w, out);
}

// Round 14
// 268.140 us; speedup vs baseline: 1.0562x; 1.0562x over previous
//
#include <hip/hip_runtime.h>

#define S_LEN 1024
#define B_SZ 8
#define F_IN_D 256
#define E_DIM 512
#define INNER_D 1024
#define NH_D 4
#define DH_D 256
#define NROW (B_SZ * S_LEN)   // 8192

typedef _Float16 half8 __attribute__((ext_vector_type(8)));
typedef _Float16 half4_t __attribute__((ext_vector_type(4)));
typedef float v4f __attribute__((ext_vector_type(4)));

// ---------------------------------------------------------------------------
// R19: cast only x + W_in up front (all gemm_in needs). W_up / W_down casts
// ride inside ln_mul / scan_vtrans dispatches (off the critical-path head).
// ---------------------------------------------------------------------------
__global__ __launch_bounds__(256) void cast2_kernel(
    const float* __restrict__ s0, const float* __restrict__ s1,
    _Float16* __restrict__ d0, _Float16* __restrict__ d1,
    int n0, int n1)
{
  int i = (blockIdx.x * 256 + threadIdx.x) * 4;
  const float* s; _Float16* d; int off;
  if (i < n0)           { s = s0; d = d0; off = i; }
  else if (i < n0 + n1) { s = s1; d = d1; off = i - n0; }
  else return;
  float4 v = *(const float4*)(s + off);
  half4_t o = {(_Float16)v.x, (_Float16)v.y, (_Float16)v.z, (_Float16)v.w};
  *(half4_t*)(d + off) = o;
}

// ---------------------------------------------------------------------------
// Pure-f16 MFMA NT GEMM: C[M,N] = A[M,K] @ B[N,K]^T (+ bias), C f32.
// Reg-staged 128x128 structure — proven best.
// ---------------------------------------------------------------------------
#define GBM 128
#define GBN 128
#define GBK 64
#define LDKG (GBK + 8)   // 72 halves = 36 dwords stride

__global__ __launch_bounds__(256) void gemm_h16(
    const _Float16* __restrict__ A, const _Float16* __restrict__ B,
    const float* __restrict__ bias, float* __restrict__ C,
    int M, int N, int K)
{
  __shared__ __align__(16) _Float16 As[GBM][LDKG];
  __shared__ __align__(16) _Float16 Bs[GBN][LDKG];
  const int tid = threadIdx.x;
  const int lane = tid & 63, w = tid >> 6;
  const int wr = w >> 1, wc = w & 1;
  const int quad = lane >> 4, l16 = lane & 15;
  const int bm = blockIdx.y * GBM, bn = blockIdx.x * GBN;
  const int srow = tid >> 1;          // 0..127
  const int scol = (tid & 1) * 32;    // halves

  v4f acc[4][4];
#pragma unroll
  for (int i = 0; i < 4; ++i)
#pragma unroll
    for (int j = 0; j < 4; ++j) acc[i][j] = (v4f){0.f, 0.f, 0.f, 0.f};

  const _Float16* Ap = A + (size_t)(bm + srow) * K + scol;
  const _Float16* Bp = B + (size_t)(bn + srow) * K + scol;
  half8 ap[4], bp[4];
#pragma unroll
  for (int j = 0; j < 4; ++j) {
    ap[j] = *(const half8*)(Ap + j * 8);
    bp[j] = *(const half8*)(Bp + j * 8);
  }

  for (int k0 = 0; k0 < K; k0 += GBK) {
    __syncthreads();
#pragma unroll
    for (int j = 0; j < 4; ++j) {
      *(half8*)(&As[srow][scol + j * 8]) = ap[j];
      *(half8*)(&Bs[srow][scol + j * 8]) = bp[j];
    }
    __syncthreads();
    if (k0 + GBK < K) {
      const int kn = k0 + GBK;
#pragma unroll
      for (int j = 0; j < 4; ++j) {
        ap[j] = *(const half8*)(Ap + kn + j * 8);
        bp[j] = *(const half8*)(Bp + kn + j * 8);
      }
    }
#pragma unroll
    for (int kc = 0; kc < 2; ++kc) {
      half8 af[4], bf[4];
#pragma unroll
      for (int i = 0; i < 4; ++i)
        af[i] = *(const half8*)(&As[wr * 64 + i * 16 + l16][kc * 32 + quad * 8]);
#pragma unroll
      for (int j = 0; j < 4; ++j)
        bf[j] = *(const half8*)(&Bs[wc * 64 + j * 16 + l16][kc * 32 + quad * 8]);
#pragma unroll
      for (int i = 0; i < 4; ++i)
#pragma unroll
        for (int j = 0; j < 4; ++j)
          acc[i][j] = __builtin_amdgcn_mfma_f32_16x16x32_f16(af[i], bf[j], acc[i][j], 0, 0, 0);
    }
  }

#pragma unroll
  for (int j = 0; j < 4; ++j) {
    const int col = bn + wc * 64 + j * 16 + l16;
    const float bv = bias ? bias[col] : 0.f;
#pragma unroll
    for (int i = 0; i < 4; ++i) {
      const int row0 = bm + wr * 64 + i * 16 + quad * 4;
#pragma unroll
      for (int r = 0; r < 4; ++r)
        C[(size_t)(row0 + r) * N + col] = acc[i][j][r] + bv;
    }
  }
}

// ---------------------------------------------------------------------------
// R17 split-K2 GEMM for the down projection (neutral vs single-K, kept).
// ---------------------------------------------------------------------------
__global__ __launch_bounds__(256) void gemm_h16_sk(
    const _Float16* __restrict__ A, const _Float16* __restrict__ B,
    float* __restrict__ C0, float* __restrict__ C1,
    int M, int N, int Kfull, int Ksp)
{
  __shared__ __align__(16) _Float16 As[GBM][LDKG];
  __shared__ __align__(16) _Float16 Bs[GBN][LDKG];
  const int tid = threadIdx.x;
  const int lane = tid & 63, w = tid >> 6;
  const int wr = w >> 1, wc = w & 1;
  const int quad = lane >> 4, l16 = lane & 15;
  const int bm = blockIdx.y * GBM, bn = blockIdx.x * GBN;
  float* C = blockIdx.z ? C1 : C0;
  const size_t koff = (size_t)blockIdx.z * Ksp;
  const int srow = tid >> 1;
  const int scol = (tid & 1) * 32;

  v4f acc[4][4];
#pragma unroll
  for (int i = 0; i < 4; ++i)
#pragma unroll
    for (int j = 0; j < 4; ++j) acc[i][j] = (v4f){0.f, 0.f, 0.f, 0.f};

  const _Float16* Ap = A + (size_t)(bm + srow) * Kfull + koff + scol;
  const _Float16* Bp = B + (size_t)(bn + srow) * Kfull + koff + scol;
  half8 ap[4], bp[4];
#pragma unroll
  for (int j = 0; j < 4; ++j) {
    ap[j] = *(const half8*)(Ap + j * 8);
    bp[j] = *(const half8*)(Bp + j * 8);
  }

  for (int k0 = 0; k0 < Ksp; k0 += GBK) {
    __syncthreads();
#pragma unroll
    for (int j = 0; j < 4; ++j) {
      *(half8*)(&As[srow][scol + j * 8]) = ap[j];
      *(half8*)(&Bs[srow][scol + j * 8]) = bp[j];
    }
    __syncthreads();
    if (k0 + GBK < Ksp) {
      const int kn = k0 + GBK;
#pragma unroll
      for (int j = 0; j < 4; ++j) {
        ap[j] = *(const half8*)(Ap + kn + j * 8);
        bp[j] = *(const half8*)(Bp + kn + j * 8);
      }
    }
#pragma unroll
    for (int kc = 0; kc < 2; ++kc) {
      half8 af[4], bf[4];
#pragma unroll
      for (int i = 0; i < 4; ++i)
        af[i] = *(const half8*)(&As[wr * 64 + i * 16 + l16][kc * 32 + quad * 8]);
#pragma unroll
      for (int j = 0; j < 4; ++j)
        bf[j] = *(const half8*)(&Bs[wc * 64 + j * 16 + l16][kc * 32 + quad * 8]);
#pragma unroll
      for (int i = 0; i < 4; ++i)
#pragma unroll
        for (int j = 0; j < 4; ++j)
          acc[i][j] = __builtin_amdgcn_mfma_f32_16x16x32_f16(af[i], bf[j], acc[i][j], 0, 0, 0);
    }
  }

#pragma unroll
  for (int j = 0; j < 4; ++j) {
    const int col = bn + wc * 64 + j * 16 + l16;
#pragma unroll
    for (int i = 0; i < 4; ++i) {
      const int row0 = bm + wr * 64 + i * 16 + quad * 4;
#pragma unroll
      for (int r = 0; r < 4; ++r)
        C[(size_t)(row0 + r) * N + col] = acc[i][j][r];
    }
  }
}

// ---------------------------------------------------------------------------
// Up-projection GEMM (BK=64): writes x_m half as f16 (xmh), silu(z) f16 (szb).
// ---------------------------------------------------------------------------
__global__ __launch_bounds__(256) void gemm_h16_up(
    const _Float16* __restrict__ A, const _Float16* __restrict__ B,
    _Float16* __restrict__ xmh, _Float16* __restrict__ szb,
    int M, int N, int K)
{
  __shared__ __align__(16) _Float16 As[GBM][LDKG];
  __shared__ __align__(16) _Float16 Bs[GBN][LDKG];
  const int tid = threadIdx.x;
  const int lane = tid & 63, w = tid >> 6;
  const int wr = w >> 1, wc = w & 1;
  const int quad = lane >> 4, l16 = lane & 15;
  const int bm = blockIdx.y * GBM, bn = blockIdx.x * GBN;
  const int srow = tid >> 1;
  const int scol = (tid & 1) * 32;

  v4f acc[4][4];
#pragma unroll
  for (int i = 0; i < 4; ++i)
#pragma unroll
    for (int j = 0; j < 4; ++j) acc[i][j] = (v4f){0.f, 0.f, 0.f, 0.f};

  const _Float16* Ap = A + (size_t)(bm + srow) * K + scol;
  const _Float16* Bp = B + (size_t)(bn + srow) * K + scol;
  half8 ap[4], bp[4];
#pragma unroll
  for (int j = 0; j < 4; ++j) {
    ap[j] = *(const half8*)(Ap + j * 8);
    bp[j] = *(const half8*)(Bp + j * 8);
  }

  for (int k0 = 0; k0 < K; k0 += GBK) {
    __syncthreads();
#pragma unroll
    for (int j = 0; j < 4; ++j) {
      *(half8*)(&As[srow][scol + j * 8]) = ap[j];
      *(half8*)(&Bs[srow][scol + j * 8]) = bp[j];
    }
    __syncthreads();
    if (k0 + GBK < K) {
      const int kn = k0 + GBK;
#pragma unroll
      for (int j = 0; j < 4; ++j) {
        ap[j] = *(const half8*)(Ap + kn + j * 8);
        bp[j] = *(const half8*)(Bp + kn + j * 8);
      }
    }
#pragma unroll
    for (int kc = 0; kc < 2; ++kc) {
      half8 af[4], bf[4];
#pragma unroll
      for (int i = 0; i < 4; ++i)
        af[i] = *(const half8*)(&As[wr * 64 + i * 16 + l16][kc * 32 + quad * 8]);
#pragma unroll
      for (int j = 0; j < 4; ++j)
        bf[j] = *(const half8*)(&Bs[wc * 64 + j * 16 + l16][kc * 32 + quad * 8]);
#pragma unroll
      for (int i = 0; i < 4; ++i)
#pragma unroll
        for (int j = 0; j < 4; ++j)
          acc[i][j] = __builtin_amdgcn_mfma_f32_16x16x32_f16(af[i], bf[j], acc[i][j], 0, 0, 0);
    }
  }

  const bool zhalf = (bn >= INNER_D);
#pragma unroll
  for (int j = 0; j < 4; ++j) {
    const int col = bn + wc * 64 + j * 16 + l16;
    const int colm = col & (INNER_D - 1);
#pragma unroll
    for (int i = 0; i < 4; ++i) {
      const int row0 = bm + wr * 64 + i * 16 + quad * 4;
#pragma unroll
      for (int r = 0; r < 4; ++r) {
        float a = acc[i][j][r];
        if (zhalf) {
          float s = a / (1.f + __expf(-a));
          szb[(size_t)(row0 + r) * INNER_D + colm] = (_Float16)s;
        } else {
          xmh[(size_t)(row0 + r) * INNER_D + colm] = (_Float16)a;
        }
      }
    }
  }
}

// ---------------------------------------------------------------------------
__device__ __forceinline__ float block_sum4(float v, float* red, int tid) {
#pragma unroll
  for (int off = 32; off; off >>= 1) v += __shfl_xor(v, off);
  if ((tid & 63) == 0) red[tid >> 6] = v;
  __syncthreads();
  float t = red[0] + red[1] + red[2] + red[3];
  __syncthreads();
  return t;
}

// ---------------------------------------------------------------------------
// R19: ln_mul + W_up cast in one dispatch.
// ---------------------------------------------------------------------------
__global__ __launch_bounds__(256) void ln_mul_castwup_kernel(
    const float* __restrict__ in, const float* __restrict__ w,
    _Float16* __restrict__ out,
    const float* __restrict__ wup_src, _Float16* __restrict__ wup_dst,
    int nwup, int ncast)
{
  __shared__ float red[4];
  const int tid = threadIdx.x;
  if ((int)blockIdx.x < ncast) {
    int i = (blockIdx.x * 256 + tid) * 4;
    if (i < nwup) {
      float4 v = *(const float4*)(wup_src + i);
      half4_t o = {(_Float16)v.x, (_Float16)v.y, (_Float16)v.z, (_Float16)v.w};
      *(half4_t*)(wup_dst + i) = o;
    }
    return;
  }
  const int row = blockIdx.x - ncast;
  const float* p = in + (size_t)row * E_DIM;
  float v0 = p[tid], v1 = p[tid + 256];
  float mean = block_sum4(v0 + v1, red, tid) * (1.f / E_DIM);
  float d0 = v0 - mean, d1 = v1 - mean;
  float var = block_sum4(d0 * d0 + d1 * d1, red, tid) * (1.f / E_DIM);
  float rstd = rsqrtf(var + 1e-5f);
  out[(size_t)row * E_DIM + tid] = (_Float16)(d0 * rstd * w[tid]);
  out[(size_t)row * E_DIM + tid + 256] = (_Float16)(d1 * rstd * w[tid + 256]);
}

// final_ln: out = LN(res + y1 + y2) * w   (y2 from split-K partial)
__global__ __launch_bounds__(256) void final_ln_kernel(
    const float* __restrict__ res, const float* __restrict__ y1,
    const float* __restrict__ y2,
    const float* __restrict__ w, float* __restrict__ out)
{
  __shared__ float red[4];
  const int row = blockIdx.x;
  const int tid = threadIdx.x;
  const size_t base = (size_t)row * E_DIM;
  float v0 = res[base + tid] + y1[base + tid] + y2[base + tid];
  float v1 = res[base + tid + 256] + y1[base + tid + 256] + y2[base + tid + 256];
  float mean = block_sum4(v0 + v1, red, tid) * (1.f / E_DIM);
  float d0 = v0 - mean, d1 = v1 - mean;
  float var = block_sum4(d0 * d0 + d1 * d1, red, tid) * (1.f / E_DIM);
  float rstd = rsqrtf(var + 1e-5f);
  out[base + tid] = d0 * rstd * w[tid];
  out[base + tid + 256] = d1 * rstd * w[tid + 256];
}

// ---------------------------------------------------------------------------
// Fused conv+silu + headwise q/k/v + gates, 4 rows per block.
// ---------------------------------------------------------------------------
__global__ __launch_bounds__(256) void chg_kernel(
    const _Float16* __restrict__ xm, const float* __restrict__ cw,
    const float* __restrict__ cb,
    const float* __restrict__ Wq, const float* __restrict__ Wk,
    const float* __restrict__ Wv,
    const float* __restrict__ Wig, const float* __restrict__ big,
    const float* __restrict__ Wfg, const float* __restrict__ bfg,
    _Float16* __restrict__ xch, _Float16* __restrict__ qh,
    _Float16* __restrict__ khb, _Float16* __restrict__ vhb,
    float* __restrict__ ig, float* __restrict__ fg)
{
  __shared__ float red[4][32];
  const int tid = threadIdx.x;
  const int lane = tid & 63, wid = tid >> 6;
  const int row0 = blockIdx.x * 4;
  const int sl0 = row0 & (S_LEN - 1);
  const int c = tid * 4;

  float t[7][4];
#pragma unroll
  for (int j = 0; j < 7; ++j) {
    const int off = j - 3;
    if (sl0 + off < 0) {
      t[j][0] = t[j][1] = t[j][2] = t[j][3] = 0.f;
    } else {
      half4_t hv = *(const half4_t*)(xm + (size_t)(row0 + off) * INNER_D + c);
      t[j][0] = (float)hv.x; t[j][1] = (float)hv.y;
      t[j][2] = (float)hv.z; t[j][3] = (float)hv.w;
    }
  }
  float wct[4][4];
#pragma unroll
  for (int j = 0; j < 4; ++j) {
    float4 wc4 = *(const float4*)(cw + (c + j) * 4);
    wct[j][0] = wc4.x; wct[j][1] = wc4.y; wct[j][2] = wc4.z; wct[j][3] = wc4.w;
  }
  float4 cb4 = *(const float4*)(cb + c);
  const float cbs[4] = {cb4.x, cb4.y, cb4.z, cb4.w};
  float wqm[16], wkm[16], wvm[16];
#pragma unroll
  for (int i = 0; i < 4; ++i) {
    float4 a = *(const float4*)(Wq + tid * 16 + i * 4);
    float4 bq = *(const float4*)(Wk + tid * 16 + i * 4);
    float4 cq = *(const float4*)(Wv + tid * 16 + i * 4);
    wqm[i * 4] = a.x; wqm[i * 4 + 1] = a.y; wqm[i * 4 + 2] = a.z; wqm[i * 4 + 3] = a.w;
    wkm[i * 4] = bq.x; wkm[i * 4 + 1] = bq.y; wkm[i * 4 + 2] = bq.z; wkm[i * 4 + 3] = bq.w;
    wvm[i * 4] = cq.x; wvm[i * 4 + 1] = cq.y; wvm[i * 4 + 2] = cq.z; wvm[i * 4 + 3] = cq.w;
  }

  float q4[4][4], k4[4][4], v4m[4][4];
#pragma unroll
  for (int r = 0; r < 4; ++r) {
    float xc4[4];
#pragma unroll
    for (int j = 0; j < 4; ++j) {
      float a = cbs[j] + wct[j][0] * t[r][j] + wct[j][1] * t[r + 1][j]
                       + wct[j][2] * t[r + 2][j] + wct[j][3] * t[r + 3][j];
      xc4[j] = a / (1.f + __expf(-a));
    }
#pragma unroll
    for (int i = 0; i < 4; ++i) {
      q4[r][i] = wqm[i * 4] * xc4[0] + wqm[i * 4 + 1] * xc4[1]
               + wqm[i * 4 + 2] * xc4[2] + wqm[i * 4 + 3] * xc4[3];
      k4[r][i] = wkm[i * 4] * xc4[0] + wkm[i * 4 + 1] * xc4[1]
               + wkm[i * 4 + 2] * xc4[2] + wkm[i * 4 + 3] * xc4[3];
      v4m[r][i] = wvm[i * 4] * t[r + 3][0] + wvm[i * 4 + 1] * t[r + 3][1]
                + wvm[i * 4 + 2] * t[r + 3][2] + wvm[i * 4 + 3] * t[r + 3][3];
    }
    const size_t base = (size_t)(row0 + r) * INNER_D + c;
    half4_t xo = {(_Float16)xc4[0], (_Float16)xc4[1], (_Float16)xc4[2], (_Float16)xc4[3]};
    half4_t qo = {(_Float16)q4[r][0], (_Float16)q4[r][1], (_Float16)q4[r][2], (_Float16)q4[r][3]};
    half4_t ko = {(_Float16)k4[r][0], (_Float16)k4[r][1], (_Float16)k4[r][2], (_Float16)k4[r][3]};
    half4_t vo = {(_Float16)v4m[r][0], (_Float16)v4m[r][1], (_Float16)v4m[r][2], (_Float16)v4m[r][3]};
    *(half4_t*)(xch + base) = xo;
    *(half4_t*)(qh + base) = qo;
    *(half4_t*)(khb + base) = ko;
    *(half4_t*)(vhb + base) = vo;
  }

  float vals[32];
#pragma unroll
  for (int g = 0; g < 8; ++g) {
    const float* wb = (g < 4 ? Wig : Wfg) + (g & 3) * 3072 + c;
    float4 w1 = *(const float4*)(wb);
    float4 w2 = *(const float4*)(wb + 1024);
    float4 w3 = *(const float4*)(wb + 2048);
#pragma unroll
    for (int r = 0; r < 4; ++r) {
      vals[g * 4 + r] =
          q4[r][0] * w1.x + q4[r][1] * w1.y + q4[r][2] * w1.z + q4[r][3] * w1.w
        + k4[r][0] * w2.x + k4[r][1] * w2.y + k4[r][2] * w2.z + k4[r][3] * w2.w
        + v4m[r][0] * w3.x + v4m[r][1] * w3.y + v4m[r][2] * w3.z + v4m[r][3] * w3.w;
    }
  }
#pragma unroll
  for (int i = 0; i < 32; ++i) {
    float x = vals[i];
#pragma unroll
    for (int off = 32; off; off >>= 1) x += __shfl_xor(x, off);
    vals[i] = x;
  }
  if (lane == 0) {
#pragma unroll
    for (int i = 0; i < 32; ++i) red[wid][i] = vals[i];
  }
  __syncthreads();
  if (tid < 32) {
    float sm = red[0][tid] + red[1][tid] + red[2][tid] + red[3][tid];
    const int g = tid >> 2, r = tid & 3;
    const int h = g & 3;
    const int b = row0 >> 10;
    const size_t oidx = (size_t)(b * NH_D + h) * S_LEN + sl0 + r;
    if (g < 4) ig[oidx] = sm + big[h];
    else       fg[oidx] = sm + bfg[h];
  }
}

// ---------------------------------------------------------------------------
__device__ __forceinline__ float logsigf(float x) {
  return fminf(x, 0.f) - log1pf(__expf(-fabsf(x)));
}

// ---------------------------------------------------------------------------
// R18 merged scan + vtrans + R19 W_down cast tail.
// Blocks 0-31 scan; 32..2079 vtrans; 2080.. cast W_down.
// ---------------------------------------------------------------------------
__global__ __launch_bounds__(256) void scan_vtrans_kernel(
    const float* __restrict__ ig, const float* __restrict__ fg,
    float* __restrict__ m_, float* __restrict__ rmax_, float* __restrict__ maxd_,
    float* __restrict__ em_,
    const _Float16* __restrict__ vb, _Float16* __restrict__ vt,
    const float* __restrict__ wdn_src, _Float16* __restrict__ wdn_dst,
    int nwdn)
{
  __shared__ float sc[256];
  __shared__ _Float16 tile[64][68];
  const int tid = threadIdx.x;

  if (blockIdx.x < 32) {
    // ---- scan body (bh = blockIdx.x) ----
    const int bh = blockIdx.x;
    const size_t base = (size_t)bh * S_LEN + tid * 4;
    float4 f4 = *(const float4*)(fg + base);
    float4 i4 = *(const float4*)(ig + base);
    float l0 = logsigf(f4.x), l1 = logsigf(f4.y), l2 = logsigf(f4.z), l3 = logsigf(f4.w);
    float p0 = l0, p1 = p0 + l1, p2 = p1 + l2, p3 = p2 + l3;
    sc[tid] = p3;
    __syncthreads();
    for (int off = 1; off < 256; off <<= 1) {
      float o = (tid >= off) ? sc[tid - off] : 0.f;
      __syncthreads();
      sc[tid] += o;
      __syncthreads();
    }
    float aoff = (tid == 0) ? 0.f : sc[tid - 1];
    __syncthreads();
    float a0 = aoff + p0, a1 = aoff + p1, a2 = aoff + p2, a3 = aoff + p3;
    float m0 = i4.x - a0, m1 = i4.y - a1, m2 = i4.z - a2, m3 = i4.w - a3;
    float x0 = m0, x1 = fmaxf(x0, m1), x2 = fmaxf(x1, m2), x3 = fmaxf(x2, m3);
    sc[tid] = x3;
    __syncthreads();
    for (int off = 1; off < 256; off <<= 1) {
      float o = (tid >= off) ? sc[tid - off] : -1e30f;
      __syncthreads();
      sc[tid] = fmaxf(sc[tid], o);
      __syncthreads();
    }
    float moff = (tid == 0) ? -1e30f : sc[tid - 1];
    float tmax = sc[tid | 15];
    float r0 = fmaxf(moff, x0), r1 = fmaxf(moff, x1), r2 = fmaxf(moff, x2), r3 = fmaxf(moff, x3);
    const float scale = 0.0625f;
    float4 mo = {m0, m1, m2, m3};
    float4 ro = {r0, r1, r2, r3};
    float4 dd = {a0 + r0, a1 + r1, a2 + r2, a3 + r3};
    float4 eo = {scale * __expf(m0 - tmax), scale * __expf(m1 - tmax),
                 scale * __expf(m2 - tmax), scale * __expf(m3 - tmax)};
    *(float4*)(m_ + base) = mo;
    *(float4*)(rmax_ + base) = ro;
    *(float4*)(maxd_ + base) = dd;
    *(float4*)(em_ + base) = eo;
    return;
  }

  if (blockIdx.x >= 32 + 2048) {
    // ---- W_down cast tail ----
    int i = ((blockIdx.x - 32 - 2048) * 256 + tid) * 4;
    if (i < nwdn) {
      float4 v = *(const float4*)(wdn_src + i);
      half4_t o = {(_Float16)v.x, (_Float16)v.y, (_Float16)v.z, (_Float16)v.w};
      *(half4_t*)(wdn_dst + i) = o;
    }
    return;
  }

  // ---- vtrans body ----
  const int vbid = blockIdx.x - 32;
  const int dt = vbid & 15, st = (vbid >> 4) & 15, b = vbid >> 8;
  const int c4 = (tid & 15) * 4, rr = tid >> 4;
  const int s0 = st * 64, d0 = dt * 64;
#pragma unroll
  for (int i = 0; i < 4; ++i) {
    int r = rr + i * 16;
    half4_t v = *(const half4_t*)(vb + ((size_t)(b * S_LEN + s0 + r)) * INNER_D + d0 + c4);
    tile[r][c4 + 0] = v.x; tile[r][c4 + 1] = v.y;
    tile[r][c4 + 2] = v.z; tile[r][c4 + 3] = v.w;
  }
  __syncthreads();
#pragma unroll
  for (int i = 0; i < 4; ++i) {
    int dd = rr + i * 16;
    half4_t o = {tile[c4 + 0][dd], tile[c4 + 1][dd], tile[c4 + 2][dd], tile[c4 + 3][dd]};
    *(half4_t*)(vt + ((size_t)(b * INNER_D + d0 + dd)) * S_LEN + s0 + c4) = o;
  }
}

// ---------------------------------------------------------------------------
// R16 merged uniform-work attention (57.6 us, verified): 256 blocks x 512
// threads; bh = bid&31 (same-bh blocks at bid stride 32 = one XCD -> K/V
// L2-local, FETCH 41 MB), j = bid>>5. Waves 0-3: q-block (15-j); waves
// 4-7: q-block (j); shared K/V staging. Exactly 17 compute-wave-tiles per
// block, 8 waves resident throughout. (R20's wave-private variant without
// the mid-tile barrier regressed to 283 us — the 3-barrier form is
// load-bearing: it enables 2x K/V fragment reuse and keeps waves
// phase-locked against staging interference. Do not remove.)
// ---------------------------------------------------------------------------
#define KP 264
#define VP 72
#define PP 72

__global__ __launch_bounds__(512, 1) void attn_blk_kernel(
    const _Float16* __restrict__ qh, const _Float16* __restrict__ khb,
    const _Float16* __restrict__ vt,
    const float* __restrict__ m_, const float* __restrict__ em,
    const float* __restrict__ rmax_, const float* __restrict__ maxd_,
    const float* __restrict__ mhln_w, const float* __restrict__ skip,
    const _Float16* __restrict__ xch, const _Float16* __restrict__ szb,
    _Float16* __restrict__ hstate)
{
  __shared__ __align__(16) _Float16 Ks[64][KP];
  __shared__ __align__(16) _Float16 Vs[256][VP];
  __shared__ __align__(16) _Float16 Pl[2][64][PP];
  __shared__ float cred[2][2][64];
  const int tid = threadIdx.x;
  const int lane = tid & 63, wid = tid >> 6;      // wid 0..7
  const int quad = lane >> 4, l16 = lane & 15;
  const int grp = wid >> 2;          // 0 = long q-block, 1 = short q-block
  const int wr = (wid >> 1) & 1;     // row-half within group
  const int ws = wid & 1;            // QK: key-half; PV: d-half
  const int bh = blockIdx.x & 31;    // XCD-local: same bh -> bid stride 32
  const int j = blockIdx.x >> 5;     // pair index 0..7
  const int qblk = grp ? j : (15 - j);
  const int ntile = qblk + 1;        // this group's k-tiles
  const int Tmax = 16 - j;           // block loop count (= long group's ntile)
  const int qb0 = qblk * 64;
  const int h = bh & 3, b = bh >> 2;
  const float* rmaxp = rmax_ + (size_t)bh * S_LEN;
  const float* emp = em + (size_t)bh * S_LEN;
  const float* mp = m_ + (size_t)bh * S_LEN;
  const float* maxdp = maxd_ + (size_t)bh * S_LEN;
  const float scale = 0.0625f;

  const _Float16* kg = khb + ((size_t)(b * S_LEN)) * INNER_D + h * DH_D;
  const _Float16* vg = vt + ((size_t)(b * INNER_D + h * DH_D)) * S_LEN;
  // staging split over 512 threads: 4 half8 K + 4 half8 V per thread
  const int krow_s = tid >> 5;          // 0..15
  const int kcol_s = (tid & 31) * 8;    // 0..248
  const int vrow_s = tid >> 3;          // 0..63
  const int vcol_s = (tid & 7) * 8;     // 0..56

  half8 kpre[4], vpre[4];
#pragma unroll
  for (int i = 0; i < 4; ++i) {
    kpre[i] = *(const half8*)(kg + (size_t)(i * 16 + krow_s) * INNER_D + kcol_s);
    vpre[i] = *(const half8*)(vg + (size_t)(i * 64 + vrow_s) * S_LEN + vcol_s);
  }

  // Q fragments for this wave's 32 rows (2 groups of 16).
  half8 qf[2][8];
#pragma unroll
  for (int g = 0; g < 2; ++g) {
    const _Float16* qrow =
        qh + ((size_t)(b * S_LEN + qb0 + wr * 32 + g * 16 + l16)) * INNER_D
           + h * DH_D + quad * 8;
#pragma unroll
    for (int c = 0; c < 8; ++c) qf[g][c] = *(const half8*)(qrow + c * 32);
  }

  v4f acc[2][8];
#pragma unroll
  for (int g = 0; g < 2; ++g)
#pragma unroll
    for (int nc = 0; nc < 8; ++nc) acc[g][nc] = (v4f){0.f, 0.f, 0.f, 0.f};
  float rsum[8] = {0.f, 0.f, 0.f, 0.f, 0.f, 0.f, 0.f, 0.f};
  float rmax_row[8];
#pragma unroll
  for (int g = 0; g < 2; ++g)
#pragma unroll
    for (int r = 0; r < 4; ++r)
      rmax_row[g * 4 + r] = rmaxp[qb0 + wr * 32 + g * 16 + quad * 4 + r];

  for (int tt = 0; tt < Tmax; ++tt) {
    const int t0 = tt * 64;
    const bool active = (tt < ntile);
    const bool diag = (tt == ntile - 1);
    __syncthreads();
#pragma unroll
    for (int i = 0; i < 4; ++i) {
      *(half8*)(&Ks[i * 16 + krow_s][kcol_s]) = kpre[i];
      *(half8*)(&Vs[i * 64 + vrow_s][vcol_s]) = vpre[i];
    }
    __syncthreads();
    if (tt + 1 < Tmax) {
      const int tn = t0 + 64;
#pragma unroll
      for (int i = 0; i < 4; ++i) {
        kpre[i] = *(const half8*)(kg + (size_t)(tn + i * 16 + krow_s) * INNER_D + kcol_s);
        vpre[i] = *(const half8*)(vg + (size_t)(i * 64 + vrow_s) * S_LEN + tn + vcol_s);
      }
    }
    if (active) {
      float rowfac[8];
      if (!diag) {
        const float rtile = rmaxp[t0 + 63];
#pragma unroll
        for (int gr = 0; gr < 8; ++gr) rowfac[gr] = __expf(rtile - rmax_row[gr]);
      }
      // ---- QK^T: rows [wr*32,+32) x keys [ws*32,+32).
#pragma unroll
      for (int ks = 0; ks < 2; ++ks) {
        v4f sg[2];
        sg[0] = (v4f){0.f, 0.f, 0.f, 0.f};
        sg[1] = (v4f){0.f, 0.f, 0.f, 0.f};
#pragma unroll
        for (int c = 0; c < 8; ++c) {
          half8 kf = *(const half8*)(&Ks[ws * 32 + ks * 16 + l16][c * 32 + quad * 8]);
          sg[0] = __builtin_amdgcn_mfma_f32_16x16x32_f16(qf[0][c], kf, sg[0], 0, 0, 0);
          sg[1] = __builtin_amdgcn_mfma_f32_16x16x32_f16(qf[1][c], kf, sg[1], 0, 0, 0);
        }
        const int t = t0 + ws * 32 + ks * 16 + l16;
        if (diag) {
          const float mt = mp[t];
#pragma unroll
          for (int g = 0; g < 2; ++g)
#pragma unroll
            for (int r = 0; r < 4; ++r) {
              const int srow = qb0 + wr * 32 + g * 16 + quad * 4 + r;
              float cc = (t <= srow)
                           ? sg[g][r] * scale * __expf(mt - rmax_row[g * 4 + r]) : 0.f;
              rsum[g * 4 + r] += cc;
              Pl[grp][wr * 32 + g * 16 + quad * 4 + r][ws * 32 + ks * 16 + l16] = (_Float16)cc;
            }
        } else {
          const float emv = emp[t];
#pragma unroll
          for (int g = 0; g < 2; ++g)
#pragma unroll
            for (int r = 0; r < 4; ++r) {
              float cc = sg[g][r] * emv * rowfac[g * 4 + r];
              rsum[g * 4 + r] += cc;
              Pl[grp][wr * 32 + g * 16 + quad * 4 + r][ws * 32 + ks * 16 + l16] = (_Float16)cc;
            }
        }
      }
    }
    __syncthreads();   // P visible within each group
    if (active) {
      // ---- PV: rows [wr*32,+32) x d-cols [ws*128,+128), full k=64.
      half8 pf[2][2];
#pragma unroll
      for (int g = 0; g < 2; ++g) {
        pf[g][0] = *(const half8*)(&Pl[grp][wr * 32 + g * 16 + l16][quad * 8]);
        pf[g][1] = *(const half8*)(&Pl[grp][wr * 32 + g * 16 + l16][32 + quad * 8]);
      }
#pragma unroll
      for (int nc = 0; nc < 8; ++nc) {
        half8 vf0 = *(const half8*)(&Vs[ws * 128 + nc * 16 + l16][quad * 8]);
        half8 vf1 = *(const half8*)(&Vs[ws * 128 + nc * 16 + l16][32 + quad * 8]);
        acc[0][nc] = __builtin_amdgcn_mfma_f32_16x16x32_f16(pf[0][0], vf0, acc[0][nc], 0, 0, 0);
        acc[0][nc] = __builtin_amdgcn_mfma_f32_16x16x32_f16(pf[0][1], vf1, acc[0][nc], 0, 0, 0);
        acc[1][nc] = __builtin_amdgcn_mfma_f32_16x16x32_f16(pf[1][0], vf0, acc[1][nc], 0, 0, 0);
        acc[1][nc] = __builtin_amdgcn_mfma_f32_16x16x32_f16(pf[1][1], vf1, acc[1][nc], 0, 0, 0);
      }
    }
  }

  // ---- row-sum across l16, then across the two key-half waves via LDS.
#pragma unroll
  for (int gr = 0; gr < 8; ++gr) {
    float rs = rsum[gr];
    rs += __shfl_xor(rs, 1); rs += __shfl_xor(rs, 2);
    rs += __shfl_xor(rs, 4); rs += __shfl_xor(rs, 8);
    rsum[gr] = rs;
  }
  if (l16 == 0) {
#pragma unroll
    for (int g = 0; g < 2; ++g)
#pragma unroll
      for (int r = 0; r < 4; ++r)
        cred[grp][ws][wr * 32 + g * 16 + quad * 4 + r] = rsum[g * 4 + r];
  }
  __syncthreads();
  float inv[8];
#pragma unroll
  for (int g = 0; g < 2; ++g)
#pragma unroll
    for (int r = 0; r < 4; ++r) {
      const int row = wr * 32 + g * 16 + quad * 4 + r;
      float rs = cred[grp][0][row] + cred[grp][1][row];
      float md = maxdp[qb0 + row];
      float n = fmaxf(fabsf(rs), __expf(-md));
      inv[g * 4 + r] = 1.f / (n + 1e-6f);
    }
#pragma unroll
  for (int g = 0; g < 2; ++g)
#pragma unroll
    for (int nc = 0; nc < 8; ++nc)
#pragma unroll
      for (int r = 0; r < 4; ++r) acc[g][nc][r] *= inv[g * 4 + r];

  // ---- mean over d: partial (128 cols) per wave, combined across d-halves.
  __syncthreads();
  float mean[8];
#pragma unroll
  for (int gr = 0; gr < 8; ++gr) {
    const int g = gr >> 2, r = gr & 3;
    float sm = 0.f;
#pragma unroll
    for (int nc = 0; nc < 8; ++nc) sm += acc[g][nc][r];
    sm += __shfl_xor(sm, 1); sm += __shfl_xor(sm, 2);
    sm += __shfl_xor(sm, 4); sm += __shfl_xor(sm, 8);
    if (l16 == 0) cred[grp][ws][wr * 32 + g * 16 + quad * 4 + r] = sm;
  }
  __syncthreads();
#pragma unroll
  for (int gr = 0; gr < 8; ++gr) {
    const int g = gr >> 2, r = gr & 3;
    const int row = wr * 32 + g * 16 + quad * 4 + r;
    mean[gr] = (cred[grp][0][row] + cred[grp][1][row]) * (1.f / DH_D);
  }
  __syncthreads();
  float rstd[8];
#pragma unroll
  for (int gr = 0; gr < 8; ++gr) {
    const int g = gr >> 2, r = gr & 3;
    float sq = 0.f;
#pragma unroll
    for (int nc = 0; nc < 8; ++nc) { float d = acc[g][nc][r] - mean[gr]; sq += d * d; }
    sq += __shfl_xor(sq, 1); sq += __shfl_xor(sq, 2);
    sq += __shfl_xor(sq, 4); sq += __shfl_xor(sq, 8);
    if (l16 == 0) cred[grp][ws][wr * 32 + g * 16 + quad * 4 + r] = sq;
  }
  __syncthreads();
#pragma unroll
  for (int gr = 0; gr < 8; ++gr) {
    const int g = gr >> 2, r = gr & 3;
    const int row = wr * 32 + g * 16 + quad * 4 + r;
    rstd[gr] = rsqrtf((cred[grp][0][row] + cred[grp][1][row]) * (1.f / DH_D) + 1e-5f);
  }

  // ---- epilogue: LN * w + skip*xc, * silu(z); write f16.
#pragma unroll
  for (int nc = 0; nc < 8; ++nc) {
    const int d = h * DH_D + ws * 128 + nc * 16 + l16;
    const float w = mhln_w[d];
    const float sk = skip[d];
#pragma unroll
    for (int g = 0; g < 2; ++g)
#pragma unroll
      for (int r = 0; r < 4; ++r) {
        const size_t row = (size_t)(b * S_LEN + qb0 + wr * 32 + g * 16 + quad * 4 + r);
        float xcv = (float)xch[row * INNER_D + d];
        float sz = (float)szb[row * INNER_D + d];
        float o = ((acc[g][nc][r] - mean[g * 4 + r]) * rstd[g * 4 + r] * w + sk * xcv) * sz;
        hstate[row * INNER_D + d] = (_Float16)o;
      }
  }
}

// ---------------------------------------------------------------------------
extern "C" void kernel_launch(void* const* d_in, const int* in_sizes, int n_in,
                              void* d_out, int out_size, void* d_ws, size_t ws_size,
                              hipStream_t stream)
{
  const float* x      = (const float*)d_in[0];
  const float* W_in   = (const float*)d_in[1];
  const float* b_in   = (const float*)d_in[2];
  const float* ln1_w  = (const float*)d_in[3];
  const float* W_up   = (const float*)d_in[4];
  const float* conv_w = (const float*)d_in[5];
  const float* conv_b = (const float*)d_in[6];
  const float* Wq     = (const float*)d_in[7];
  const float* Wk     = (const float*)d_in[8];
  const float* Wv     = (const float*)d_in[9];
  const float* W_ig   = (const float*)d_in[10];
  const float* b_ig   = (const float*)d_in[11];
  const float* W_fg   = (const float*)d_in[12];
  const float* b_fg   = (const float*)d_in[13];
  const float* mhln_w = (const float*)d_in[14];
  const float* skip   = (const float*)d_in[15];
  const float* W_down = (const float*)d_in[16];
  const float* ln_post_w = (const float*)d_in[17];
  float* out = (float*)d_out;

  float* ws = (float*)d_ws;
  size_t o = 0;
  float* xp     = ws + o; o += (size_t)NROW * E_DIM;
  float* hbuf   = ws + o; o += (size_t)NROW * E_DIM;
  _Float16* h16 = (_Float16*)(ws + o);
  size_t ho = 0;
  _Float16* xh      = h16 + ho; ho += (size_t)NROW * F_IN_D;
  _Float16* WinH    = h16 + ho; ho += (size_t)E_DIM * F_IN_D;
  _Float16* WupH    = h16 + ho; ho += (size_t)2 * INNER_D * E_DIM;
  _Float16* WdownH  = h16 + ho; ho += (size_t)E_DIM * INNER_D;
  _Float16* hh      = h16 + ho; ho += (size_t)NROW * E_DIM;
  _Float16* xmh     = h16 + ho; ho += (size_t)NROW * INNER_D;
  _Float16* szb     = h16 + ho; ho += (size_t)NROW * INNER_D;
  _Float16* xch     = h16 + ho; ho += (size_t)NROW * INNER_D;
  _Float16* qh      = h16 + ho; ho += (size_t)NROW * INNER_D;
  _Float16* khb     = h16 + ho; ho += (size_t)NROW * INNER_D;
  _Float16* vhb     = h16 + ho; ho += (size_t)NROW * INNER_D;
  _Float16* vtb     = h16 + ho; ho += (size_t)NROW * INNER_D;
  _Float16* hstateH = h16 + ho; ho += (size_t)NROW * INNER_D;

  const int GSZ = B_SZ * NH_D * S_LEN;  // 32768
  float* igb   = hbuf;
  float* fgb   = hbuf + GSZ;
  float* mb    = hbuf + 2 * GSZ;
  float* rmaxb = hbuf + 3 * GSZ;
  float* maxdb = hbuf + 4 * GSZ;
  float* emb   = hbuf + 5 * GSZ;
  // split-K partials reuse qh/khb (dead after attention).
  float* yb1 = (float*)qh;
  float* yb2 = (float*)khb;

  dim3 blk(256);
  const int nx = NROW * F_IN_D;                // 2,097,152
  const int nwi = E_DIM * F_IN_D;              //   131,072
  const int nwu = 2 * INNER_D * E_DIM;         // 1,048,576
  const int nwd = E_DIM * INNER_D;             //   524,288
  const int ncast_up = nwu / 4 / 256;          // 1024 blocks
  const int ncast_dn = nwd / 4 / 256;          //  512 blocks

  cast2_kernel<<<(nx + nwi) / 4 / 256, blk, 0, stream>>>(
      x, W_in, xh, WinH, nx, nwi);
  gemm_h16<<<dim3(E_DIM / GBN, NROW / GBM), blk, 0, stream>>>(
      xh, WinH, b_in, xp, NROW, E_DIM, F_IN_D);
  ln_mul_castwup_kernel<<<ncast_up + NROW, blk, 0, stream>>>(
      xp, ln1_w, hh, W_up, WupH, nwu, ncast_up);
  gemm_h16_up<<<dim3(2 * INNER_D / GBN, NROW / GBM), blk, 0, stream>>>(
      hh, WupH, xmh, szb, NROW, 2 * INNER_D, E_DIM);
  chg_kernel<<<NROW / 4, blk, 0, stream>>>(
      xmh, conv_w, conv_b, Wq, Wk, Wv, W_ig, b_ig, W_fg, b_fg,
      xch, qh, khb, vhb, igb, fgb);
  scan_vtrans_kernel<<<32 + 2048 + ncast_dn, blk, 0, stream>>>(
      igb, fgb, mb, rmaxb, maxdb, emb, vhb, vtb, W_down, WdownH, nwd);
  attn_blk_kernel<<<256, dim3(512), 0, stream>>>(
      qh, khb, vtb, mb, emb, rmaxb, maxdb, mhln_w, skip, xch, szb, hstateH);
  gemm_h16_sk<<<dim3(E_DIM / GBN, NROW / GBM, 2), blk, 0, stream>>>(
      hstateH, WdownH, yb1, yb2, NROW, E_DIM, INNER_D, INNER_D / 2);
  final_ln_kernel<<<NROW, blk, 0, stream>>>(xp, yb1, yb2, ln_post_w, out);
}